// Round 6
// baseline (91.674 us; speedup 1.0000x reference)
//
#include <hip/hip_runtime.h>
#include <math.h>

#define KS     7
#define PADW   3
#define H      56
#define W      56
#define HW     (H * W)           // 3136
#define TILE   8
#define PATCH  14                // TILE + KS - 1
#define PPOS   (PATCH * PATCH)   // 196
#define PADH   62                // H + 2*PADW
#define KVROW  64                // padded kv row stride (float2 units)
#define KVPLN  (PADH * KVROW)    // 3968 float2 per (bg,dch) plane
#define KVGRP  (8 * KVPLN)       // 31744 float2 per (b,g)
#define NPADPIX (PADH * PADH)    // 3844
// ws layout: [0, 32*KVGRP) float2 kv; then q as floats
#define QOFF_FLOATS (32 * KVGRP * 2)   // float2 -> float offset
#define QGRP  (8 * HW)                 // 25088 floats per (b,g)

#if __has_builtin(__builtin_amdgcn_exp2f)
#define EXP2F(x) __builtin_amdgcn_exp2f(x)
#else
#define EXP2F(x) exp2f(x)
#endif
#if __has_builtin(__builtin_amdgcn_rcpf)
#define RCPF(x) __builtin_amdgcn_rcpf(x)
#else
#define RCPF(x) (1.0f / (x))
#endif

#define LOG2E 1.44269504088896340736f

// ---------------- kernel 1: precompute q, k, v ----------------
__global__ __launch_bounds__(256) void qkv_pre(
    const float* __restrict__ x,
    const float* __restrict__ wq,
    const float* __restrict__ wk,
    const float* __restrict__ bk,
    const float* __restrict__ wv,
    const float* __restrict__ bv,
    float2* __restrict__ kvg,
    float* __restrict__ qg)
{
    const int tid = threadIdx.x;
    const int bg  = blockIdx.y;          // b*8 + g
    const int b   = bg >> 3;
    const int g   = bg & 7;
    const int c0  = g * 8;

    const int p = blockIdx.x * 256 + tid;     // padded pixel index
    if (p >= NPADPIX) return;
    const int py = p / PADH;
    const int px = p - py * PADH;
    const int oy = py - PADW;
    const int ox = px - PADW;
    const bool in = (oy >= 0) & (oy < H) & (ox >= 0) & (ox < W);

    const float* xg  = x + (size_t)(b * 64 + c0) * HW + oy * W + ox;
    float xv[8];
#pragma unroll
    for (int i = 0; i < 8; ++i)
        xv[i] = in ? xg[i * HW] : 0.f;

    const float* wqg = wq + g * 64;
    const float* wkg = wk + g * 64;
    const float* wvg = wv + g * 64;

    float2* kvb = kvg + (size_t)bg * KVGRP + py * KVROW + px;
#pragma unroll
    for (int dch = 0; dch < 8; ++dch) {
        float ka = bk[c0 + dch];
        float va = bv[c0 + dch];
#pragma unroll
        for (int i = 0; i < 8; ++i) {
            ka = fmaf(xv[i], wkg[dch * 8 + i], ka);
            va = fmaf(xv[i], wvg[dch * 8 + i], va);
        }
        kvb[dch * KVPLN] = make_float2(ka, va);
    }

    if (in) {
        float* qb = qg + (size_t)bg * QGRP + oy * W + ox;
#pragma unroll
        for (int dch = 0; dch < 8; ++dch) {
            float qa = 0.f;
#pragma unroll
            for (int i = 0; i < 8; ++i)
                qa = fmaf(xv[i], wqg[dch * 8 + i], qa);
            qb[dch * HW] = qa;
        }
    }
}

// ---------------- kernel 2: attention (tap loop unchanged from R5) ----------------
__global__ __launch_bounds__(256) void attn_fused(
    const float2* __restrict__ kvg,
    const float* __restrict__ qg,
    const float* __restrict__ rel_x,
    const float* __restrict__ rel_y,
    float* __restrict__ out)
{
    __shared__ float2 kvm[8][PPOS];   // identical layout to R5

    const int tid  = threadIdx.x;
    const int tile = blockIdx.x;          // 0..48
    const int bg   = blockIdx.y;          // b*8 + g
    const int b    = bg >> 3;
    const int g    = bg & 7;
    const int c0   = g * 8;

    const int tileY = tile / 7;
    const int tileX = tile - tileY * 7;
    const int h0 = tileY * TILE;
    const int w0 = tileX * TILE;

    // ---- stage kv tile from global: 1568 float2, coalesced ----
    const float2* kvb = kvg + (size_t)bg * KVGRP;
    for (int idx = tid; idx < 8 * PPOS; idx += 256) {
        const int dch = idx / PPOS;
        const int pp  = idx - dch * PPOS;
        const int py  = pp / PATCH;
        const int px  = pp - py * PATCH;
        (&kvm[0][0])[idx] = kvb[dch * KVPLN + (h0 + py) * KVROW + (w0 + px)];
    }
    __syncthreads();

    const int pix  = tid & 63;
    const int dsel = tid >> 6;            // 0..3, uniform per wave
    const int ty   = pix >> 3;
    const int tx   = pix & 7;
    const int h    = h0 + ty;
    const int w    = w0 + tx;
    const int base = ty * PATCH + tx;

    const float* qb = qg + (size_t)bg * QGRP + h * W + w;

#pragma unroll
    for (int half = 0; half < 2; ++half) {
        const int dch = half * 4 + dsel;  // uniform per wave

        const float qv  = qb[dch * HW];   // one coalesced load
        const float qv2 = qv * LOG2E;

        float qvr2[7];
#pragma unroll
        for (int i = 0; i < 7; ++i) {
            float r = (half == 0) ? rel_x[dch * 7 + i]
                                  : rel_y[(dch - 4) * 7 + i];
            qvr2[i] = qv2 * r;
        }

        const float2* kp = &kvm[dch][base];

        float l = 0.f, acc = 0.f;
#pragma unroll
        for (int i = 0; i < 7; ++i) {
            float li = 0.f, ai = 0.f;
#pragma unroll
            for (int j = 0; j < 7; ++j) {
                float2 kv = kp[i * PATCH + j];
                float addv = (half == 0) ? qvr2[i] : qvr2[j];
                float e = EXP2F(fmaf(qv2, kv.x, addv));
                li += e;
                ai = fmaf(e, kv.y, ai);
            }
            l += li;
            acc += ai;
        }

        out[((size_t)(b * 64 + c0 + dch) * H + h) * W + w] = acc * RCPF(l);
    }
}

extern "C" void kernel_launch(void* const* d_in, const int* in_sizes, int n_in,
                              void* d_out, int out_size, void* d_ws, size_t ws_size,
                              hipStream_t stream) {
    const float* x     = (const float*)d_in[0];
    const float* wq    = (const float*)d_in[1];
    const float* wk    = (const float*)d_in[2];
    const float* bk    = (const float*)d_in[3];
    const float* wv    = (const float*)d_in[4];
    const float* bv    = (const float*)d_in[5];
    const float* rel_x = (const float*)d_in[6];
    const float* rel_y = (const float*)d_in[7];

    float2* kvg = (float2*)d_ws;
    float*  qg  = (float*)d_ws + QOFF_FLOATS;

    dim3 g1((NPADPIX + 255) / 256, 32, 1);   // 16 x 32 blocks
    qkv_pre<<<g1, dim3(256), 0, stream>>>(x, wq, wk, bk, wv, bv, kvg, qg);

    dim3 g2(49, 32, 1);                      // 7x7 tiles of 8x8, b*8+g
    attn_fused<<<g2, dim3(256), 0, stream>>>(kvg, qg, rel_x, rel_y, (float*)d_out);
}

// Round 8
// 82.635 us; speedup vs baseline: 1.1094x; 1.1094x over previous
//
#include <hip/hip_runtime.h>
#include <math.h>

#define KS    7
#define PADW  3
#define H     56
#define W     56
#define HW    (H * W)        // 3136
#define TW    8              // tile width
#define TH    14             // tile height (pixels); 4 y-tiles x 14 = 56
#define PW    14             // patch width  = TW + 6
#define PH    20             // patch height = TH + 6
#define PPOS  (PH * PW)      // 280 patch positions
// LDS: float2 kv, row stride 14 (112B): each wave b64 row-read covers every
// bank exactly 4 dwords = data-minimum, conflict-free.

#if __has_builtin(__builtin_amdgcn_exp2f)
#define EXP2F(x) __builtin_amdgcn_exp2f(x)
#else
#define EXP2F(x) exp2f(x)
#endif
#if __has_builtin(__builtin_amdgcn_rcpf)
#define RCPF(x) __builtin_amdgcn_rcpf(x)
#else
#define RCPF(x) (1.0f / (x))
#endif

#define LOG2E 1.44269504088896340736f

__global__ __launch_bounds__(256, 4) void attn_fused(
    const float* __restrict__ x,
    const float* __restrict__ wq,
    const float* __restrict__ wk,
    const float* __restrict__ bk,
    const float* __restrict__ wv,
    const float* __restrict__ bv,
    const float* __restrict__ rel_x,
    const float* __restrict__ rel_y,
    float* __restrict__ out)
{
    __shared__ float2 kvm[8][PPOS];   // (k,v) interleaved, 17.9 KB

    const int tid  = threadIdx.x;
    const int tile = blockIdx.x;          // 0..27: 7 x-tiles x 4 y-tiles
    const int bg   = blockIdx.y;          // b*8 + g
    const int b    = bg >> 3;
    const int g    = bg & 7;
    const int c0   = g * 8;

    const int tileY = tile / 7;           // 0..3
    const int tileX = tile - tileY * 7;   // 0..6
    const int h0 = tileY * TH;
    const int w0 = tileX * TW;

    const float* wqg = wq + g * 64;       // block-uniform -> scalar loads
    const float* wkg = wk + g * 64;
    const float* wvg = wv + g * 64;
    const float* xg  = x + (size_t)(b * 64 + c0) * HW;

    // ---- conv phase: 280 patch positions ----
    for (int idx = tid; idx < PPOS; idx += 256) {
        const int py = idx / PW;
        const int px = idx - py * PW;
        const int oy = h0 + py - PADW;
        const int ox = w0 + px - PADW;
        const bool in = (oy >= 0) & (oy < H) & (ox >= 0) & (ox < W);
        const float* xp = xg + oy * W + ox;
        float xv[8];
#pragma unroll
        for (int i = 0; i < 8; ++i)
            xv[i] = in ? xp[i * HW] : 0.f;
#pragma unroll
        for (int dch = 0; dch < 8; ++dch) {
            float ka = bk[c0 + dch];
            float va = bv[c0 + dch];
#pragma unroll
            for (int i = 0; i < 8; ++i) {
                ka = fmaf(xv[i], wkg[dch * 8 + i], ka);
                va = fmaf(xv[i], wvg[dch * 8 + i], va);
            }
            kvm[dch][idx] = make_float2(ka, va);
        }
    }
    __syncthreads();

    // ---- attention: thread = (row-pair, tx, dsel); 2 pixels x 2 dch each ----
    // 64 lanes but only 7 row-pairs x 8 tx = 56 tasks per wave: guard rp < 7.
    // (R6 bug: rp=7 lanes wrote garbage into the neighboring tile's rows.)
    const int dsel = tid >> 6;            // 0..3, wave-uniform
    const int p    = tid & 63;
    const int rp   = p >> 3;              // row pair 0..7; 7 is INVALID
    const int tx   = p & 7;

    if (rp < 7) {
        const int y0 = 2 * rp;            // pixel rows within tile (0..12)
        const int ha = h0 + y0;
        const int w  = w0 + tx;

        // center x for both pixels
        const float* xcp = xg + ha * W + w;
        float xc0[8], xc1[8];
#pragma unroll
        for (int i = 0; i < 8; ++i) {
            xc0[i] = xcp[i * HW];
            xc1[i] = xcp[i * HW + W];
        }

        const float2* kbase0 = &kvm[0][y0 * PW + tx];

#pragma unroll
        for (int half = 0; half < 2; ++half) {
            const int dch = half * 4 + dsel;  // wave-uniform

            float qv0 = 0.f, qv1 = 0.f;
#pragma unroll
            for (int i = 0; i < 8; ++i) {
                qv0 = fmaf(xc0[i], wqg[dch * 8 + i], qv0);
                qv1 = fmaf(xc1[i], wqg[dch * 8 + i], qv1);
            }
            const float q20 = qv0 * LOG2E;
            const float q21 = qv1 * LOG2E;

            float r0[7], r1[7];           // q2 * rel per window row (or col)
#pragma unroll
            for (int i = 0; i < 7; ++i) {
                const float r = (half == 0) ? rel_x[dch * 7 + i]
                                            : rel_y[(dch - 4) * 7 + i];
                r0[i] = q20 * r;
                r1[i] = q21 * r;
            }

            const float2* kp = kbase0 + dch * PPOS;

            float l0 = 0.f, a0 = 0.f, l1 = 0.f, a1 = 0.f;
#pragma unroll
            for (int r = 0; r < 8; ++r) { // union of both pixels' window rows
                float2 kv[7];
#pragma unroll
                for (int j = 0; j < 7; ++j)
                    kv[j] = kp[r * PW + j];
                if (r < 7) {              // pixel0: window row i = r
#pragma unroll
                    for (int j = 0; j < 7; ++j) {
                        const float addv = (half == 0) ? r0[r] : r0[j];
                        const float e = EXP2F(fmaf(q20, kv[j].x, addv));
                        l0 += e;
                        a0 = fmaf(e, kv[j].y, a0);
                    }
                }
                if (r >= 1) {             // pixel1: window row i = r-1
#pragma unroll
                    for (int j = 0; j < 7; ++j) {
                        const float addv = (half == 0) ? r1[r - 1] : r1[j];
                        const float e = EXP2F(fmaf(q21, kv[j].x, addv));
                        l1 += e;
                        a1 = fmaf(e, kv[j].y, a1);
                    }
                }
            }

            float* op = out + ((size_t)(b * 64 + c0 + dch) * H + ha) * W + w;
            op[0] = a0 * RCPF(l0);
            op[W] = a1 * RCPF(l1);
        }
    }
}

extern "C" void kernel_launch(void* const* d_in, const int* in_sizes, int n_in,
                              void* d_out, int out_size, void* d_ws, size_t ws_size,
                              hipStream_t stream) {
    const float* x     = (const float*)d_in[0];
    const float* wq    = (const float*)d_in[1];
    const float* wk    = (const float*)d_in[2];
    const float* bk    = (const float*)d_in[3];
    const float* wv    = (const float*)d_in[4];
    const float* bv    = (const float*)d_in[5];
    const float* rel_x = (const float*)d_in[6];
    const float* rel_y = (const float*)d_in[7];

    dim3 grid(28, 32, 1);   // 7x4 tiles (8w x 14h), b*8+g
    attn_fused<<<grid, dim3(256), 0, stream>>>(
        x, wq, wk, bk, wv, bv, rel_x, rel_y, (float*)d_out);
}